// Round 4
// baseline (128.551 us; speedup 1.0000x reference)
//
#include <hip/hip_runtime.h>
#include <hip/hip_fp16.h>

#define N_NODES 50000
#define N_EDGES 800000
#define D 64
#define BLOCK 256

#define NBIN 256      // bins over node space
#define BINW 196      // nodes per bin; 256*196 = 50176 >= 50000
#define BCAP 3584     // per-bin capacity; Binom mean 3136, sd 56 -> +8 sigma
#define EPB 4096      // edges per binning block
#define NBINBLK 196   // ceil(800000/4096)
#define PREBLK 196    // precompute blocks, 256 nodes each (196*256 = 50176)
#define SUBS 4        // agg sub-blocks per bin
#define RNODES 49     // nodes per agg block; 4*49 = 196 = BINW
#define QCAP 1024     // per-agg-block queue; mean 784, sd 28 -> +8.5 sigma

// ---------- merged binning | precompute ------------------------------------
// Binning (blocks [0,196)): counting-sort 4096 edges into 256 node-range bins
// in LDS, write ~64B contiguous runs (no write amplification).
// Precompute (blocks [196,392)): ONE NODE PER LANE. Lane l holds its h-row in
// registers (16 coalesced-consumed float4 loads), accumulates all 64 MLP
// outputs in acc[64] (64 independent FMA chains), Wx dot is 64 lane-local
// FMAs. Zero cross-lane ops, zero LDS, no reliance on s_load formation.
// (R3's version leaned on uniform-load codegen + a serial 6-shfl reduce.)
__global__ __launch_bounds__(BLOCK) void pre_bin_kernel(
    const float* __restrict__ h, const float* __restrict__ x,
    const int* __restrict__ eidx,
    const float* __restrict__ Wh, const float* __restrict__ bh,
    const float* __restrict__ Wx, const float* __restrict__ bx,
    __half2* __restrict__ M16, float4* __restrict__ px,
    int* __restrict__ bins, int* __restrict__ gcur) {
  const unsigned b = blockIdx.x;

  if (b < NBINBLK) {                   // ---- binning path ----
    __shared__ int cnt[NBIN], ssc[NBIN], start[NBIN], cur[NBIN], gbase[NBIN];
    __shared__ int stage[EPB];         // 16 KB
    const int t = threadIdx.x;
    cnt[t] = 0;
    __syncthreads();
    const int base = (int)b * EPB;
#pragma unroll 4
    for (int k = 0; k < EPB / BLOCK; ++k) {    // pass 1: histogram
      int e = base + k * BLOCK + t;
      if (e < N_EDGES) {
        int row = eidx[e];
        if ((unsigned)row < N_NODES) atomicAdd(&cnt[row / BINW], 1);
      }
    }
    __syncthreads();
    ssc[t] = cnt[t];                   // inclusive prefix scan over 256 bins
    __syncthreads();
    for (int off = 1; off < NBIN; off <<= 1) {
      int v = (t >= off) ? ssc[t - off] : 0;
      __syncthreads();
      ssc[t] += v;
      __syncthreads();
    }
    int ex = ssc[t] - cnt[t];
    start[t] = ex;
    cur[t] = ex;
    gbase[t] = cnt[t] ? atomicAdd(&gcur[t], cnt[t]) : 0;  // one global atomic/bin
    __syncthreads();
#pragma unroll 4
    for (int k = 0; k < EPB / BLOCK; ++k) {    // pass 2: scatter into LDS stage
      int e = base + k * BLOCK + t;
      if (e < N_EDGES) {
        int row = eidx[e];
        int col = eidx[N_EDGES + e];
        if ((unsigned)row < N_NODES && (unsigned)col < N_NODES) {
          int bb = row / BINW;
          int pos = atomicAdd(&cur[bb], 1);
          stage[pos] = (bb << 24) | ((row - bb * BINW) << 16) | col;
        }
      }
    }
    __syncthreads();
    const int total = ssc[NBIN - 1];
    for (int idx = t; idx < total; idx += BLOCK) {  // coalesced run copy-out
      int e = stage[idx];
      int bb = ((unsigned)e) >> 24;
      int dst = gbase[bb] + (idx - start[bb]);
      if (dst < BCAP) bins[(size_t)bb * BCAP + dst] = e;
    }
    return;
  }

  // ---- precompute path: one node per lane, register accumulators ----
  const int pid = (int)b - NBINBLK;    // 0..195
  const int i = pid * BLOCK + threadIdx.x;
  if (i >= N_NODES) return;

  const float4* __restrict__ h4 = (const float4*)(h + (size_t)i * D);
  const float4* __restrict__ Wx4 = (const float4*)Wx;

  float acc[D];
#pragma unroll
  for (int d = 0; d < D; ++d) acc[d] = bh[d];
  float wx = bx[0];

  for (int q = 0; q < D / 4; ++q) {    // NOT unrolled: keeps code ~256 fma
    float4 hv = h4[q];                 // L1-hot after first touch of the 4 lines
    float4 wxv = Wx4[q];               // wave-uniform
    wx = fmaf(hv.x, wxv.x, fmaf(hv.y, wxv.y, fmaf(hv.z, wxv.z,
         fmaf(hv.w, wxv.w, wx))));
#pragma unroll
    for (int r = 0; r < 4; ++r) {
      float hk = (r == 0) ? hv.x : (r == 1) ? hv.y : (r == 2) ? hv.z : hv.w;
      const float4* wr4 = (const float4*)(Wh + (q * 4 + r) * D);  // uniform row
#pragma unroll
      for (int dq = 0; dq < D / 4; ++dq) {
        float4 wv = wr4[dq];
        acc[4 * dq + 0] = fmaf(hk, wv.x, acc[4 * dq + 0]);
        acc[4 * dq + 1] = fmaf(hk, wv.y, acc[4 * dq + 1]);
        acc[4 * dq + 2] = fmaf(hk, wv.z, acc[4 * dq + 2]);
        acc[4 * dq + 3] = fmaf(hk, wv.w, acc[4 * dq + 3]);
      }
    }
  }

  __half2 hh[D / 2];
#pragma unroll
  for (int j = 0; j < D / 2; ++j)
    hh[j] = __floats2half2_rn(fmaxf(acc[2 * j], 0.0f),
                              fmaxf(acc[2 * j + 1], 0.0f));
  float4* mrow = (float4*)(M16 + (size_t)i * 32);
  const float4* hhp = (const float4*)hh;
#pragma unroll
  for (int q = 0; q < 8; ++q) mrow[q] = hhp[q];  // per-lane 128B row

  float w = fmaxf(wx, 0.0f);
  px[i] = make_float4(w, w * x[(size_t)i * 3 + 0],
                      w * x[(size_t)i * 3 + 1],
                      w * x[(size_t)i * 3 + 2]);
}

// ---------- aggregate: 4 blocks/bin, row-sorted LDS queue, register acc ----
// Two passes over this bin's run (count, then scatter row-sorted into qs[]).
// Drain: 16 quarter-wave (16-lane) streams own whole rows; lane l16 owns dims
// {4*l16..4*l16+3} via float2 M16 loads; 8-deep gather pipeline (8 lines per
// VMEM instr per wave). No FP atomics anywhere.
__global__ __launch_bounds__(256) void agg_kernel(
    const float* __restrict__ h, const float* __restrict__ x,
    const int* __restrict__ bins, const int* __restrict__ gcur,
    const __half2* __restrict__ M16, const float4* __restrict__ px,
    float* __restrict__ out) {
  __shared__ int qs[QCAP];             // 4 KB
  __shared__ int hist[RNODES];
  __shared__ int rstart[RNODES + 1];
  __shared__ int rcur[RNODES];

  const int t = threadIdx.x;
  const int bin = blockIdx.x >> 2, sub = blockIdx.x & 3;
  const int lbase = sub * RNODES;      // row_local base within bin
  const int gb = bin * BINW + lbase;   // first global node
  const int R = min(RNODES, N_NODES - gb);
  if (R <= 0) return;

  if (t < RNODES) hist[t] = 0;
  __syncthreads();

  const int n = min(gcur[bin], BCAP);
  const int* bs = bins + (size_t)bin * BCAP;
  for (int i = t; i < n; i += 256) {   // pass 1: count my rows
    int e = bs[i];
    unsigned dd = (unsigned)((e >> 16) & 0xff) - (unsigned)lbase;
    if (dd < (unsigned)R) atomicAdd(&hist[dd], 1);
  }
  __syncthreads();
  if (t < 64) {                        // wave-0 shfl prefix scan over R<=49 rows
    int myh = (t < R) ? hist[t] : 0;
    int v = myh;
#pragma unroll
    for (int off = 1; off < 64; off <<= 1) {
      int u = __shfl_up(v, off);
      if (t >= off) v += u;
    }
    if (t == 0) rstart[0] = 0;
    if (t < R) { rstart[t + 1] = v; rcur[t] = v - myh; }
  }
  __syncthreads();
  for (int i = t; i < n; i += 256) {   // pass 2: scatter row-sorted
    int e = bs[i];
    unsigned dd = (unsigned)((e >> 16) & 0xff) - (unsigned)lbase;
    if (dd < (unsigned)R) {
      int pos = atomicAdd(&rcur[dd], 1);
      if (pos < QCAP) qs[pos] = e;
    }
  }
  __syncthreads();

  const float* pxf = (const float*)px;
  const float2* M2 = (const float2*)M16;   // 16 float2 per 128B row
  const int l16 = t & 15;              // lane within quarter-wave
  const int stream = t >> 4;           // 0..15
  const int wbase = t & 48;            // stream's base lane within the wave
  const size_t xb = (size_t)N_NODES * D;

  for (int rr = stream; rr < R; rr += 16) {
    int beg = min(rstart[rr], QCAP);
    int end = min(rstart[rr + 1], QCAP);
    float a0 = 0.f, a1 = 0.f, a2 = 0.f, a3 = 0.f, ps = 0.f;
    for (int qi = beg; qi < end; qi += 8) {   // 8-deep load pipeline
      float2 g[8];
      float pv[8];
      bool val[8];
#pragma unroll
      for (int j = 0; j < 8; ++j) {
        int idx = qi + j;
        val[j] = idx < end;
        int e = qs[val[j] ? idx : beg];       // LDS broadcast per stream
        int c = e & 0xffff;
        pv[j] = 0.f;
        if (val[j]) {
          g[j] = M2[(size_t)c * 16 + l16];    // 8B/lane, 128B row per stream
          if (l16 < 4) pv[j] = pxf[c * 4 + l16];
        }
      }
#pragma unroll
      for (int j = 0; j < 8; ++j)
        if (val[j]) {
          const __half2* hp = (const __half2*)&g[j];
          float2 f0 = __half22float2(hp[0]);
          float2 f1 = __half22float2(hp[1]);
          a0 += f0.x; a1 += f0.y; a2 += f1.x; a3 += f1.y;
          ps += pv[j];
        }
    }
    int gn = gb + rr;
    float4 hvv = ((const float4*)h)[(size_t)gn * 16 + l16];
    ((float4*)out)[(size_t)gn * 16 + l16] =
        make_float4(hvv.x + a0, hvv.y + a1, hvv.z + a2, hvv.w + a3);
    // ps: stream-lane 0 = sum w; lanes 1..3 = sum w*x_col components
    float W = __shfl(ps, wbase);
    float pc = __shfl(ps, wbase + l16 + 1);   // used only for l16<3
    if (l16 < 3)
      out[xb + (size_t)gn * 3 + l16] =
          fmaf(x[(size_t)gn * 3 + l16], 1.0f + W, -pc);
  }
}

// ---------------- fallback (atomic path, used only if ws too small) --------

__global__ __launch_bounds__(256) void init_out_kernel(
    const float* __restrict__ h, const float* __restrict__ x,
    float* __restrict__ out) {
  const int NH4 = N_NODES * D / 4;
  const int NT4 = (N_NODES * D + N_NODES * 3) / 4;
  int i = blockIdx.x * 256 + threadIdx.x;
  if (i >= NT4) return;
  float4 v;
  if (i < NH4) v = ((const float4*)h)[i];
  else         v = ((const float4*)x)[i - NH4];
  ((float4*)out)[i] = v;
}

__global__ __launch_bounds__(256) void edge_kernel(
    const float* __restrict__ h, const float* __restrict__ x,
    const int* __restrict__ eidx,
    const float* __restrict__ Wh, const float* __restrict__ bh,
    const float* __restrict__ Wx, const float* __restrict__ bx,
    float* __restrict__ out) {
  int e = blockIdx.x * 256 + threadIdx.x;
  if (e >= N_EDGES) return;
  int row = eidx[e];
  int col = eidx[N_EDGES + e];
  if ((unsigned)row >= N_NODES || (unsigned)col >= N_NODES) return;
  const float* hj = h + (size_t)col * D;
  float acc[D];
#pragma unroll
  for (int dd = 0; dd < D; ++dd) acc[dd] = bh[dd];
  float wsum = bx[0];
#pragma unroll 2
  for (int kg = 0; kg < D / 4; ++kg) {
    float4 hv = *(const float4*)(hj + kg * 4);
#pragma unroll
    for (int j = 0; j < 4; ++j) {
      float hk = (j == 0) ? hv.x : (j == 1) ? hv.y : (j == 2) ? hv.z : hv.w;
      int k = kg * 4 + j;
      wsum = fmaf(hk, Wx[k], wsum);
      const float* wrow = Wh + k * D;
#pragma unroll
      for (int dd = 0; dd < D; ++dd) acc[dd] = fmaf(hk, wrow[dd], acc[dd]);
    }
  }
  float* outh = out + (size_t)row * D;
#pragma unroll
  for (int dd = 0; dd < D; ++dd) atomicAdd(&outh[dd], fmaxf(acc[dd], 0.0f));
  float w = fmaxf(wsum, 0.0f);
  float* outx = out + (size_t)N_NODES * D + (size_t)row * 3;
  const float* xr = x + (size_t)row * 3;
  const float* xc = x + (size_t)col * 3;
#pragma unroll
  for (int c = 0; c < 3; ++c) atomicAdd(&outx[c], (xr[c] - xc[c]) * w);
}

// ---------------- launch ----------------

extern "C" void kernel_launch(void* const* d_in, const int* in_sizes, int n_in,
                              void* d_out, int out_size, void* d_ws, size_t ws_size,
                              hipStream_t stream) {
  const float* h    = (const float*)d_in[0];
  const float* x    = (const float*)d_in[1];
  const int*   eidx = (const int*)d_in[2];   // int64 in reference, int32 here
  const float* Wh   = (const float*)d_in[3];
  const float* bh   = (const float*)d_in[4];
  const float* Wx   = (const float*)d_in[5];
  const float* bx   = (const float*)d_in[6];
  float* out = (float*)d_out;

  // workspace: M16 6.4MB | px 0.8MB | bins 3.67MB | gcur 1KB  (~10.9MB)
  size_t need = (size_t)N_NODES * D * 2 + (size_t)N_NODES * 16 +
                (size_t)NBIN * BCAP * 4 + 1024;

  if (ws_size < need) {  // fallback: atomic path (correct, slow)
    const int NT4 = (N_NODES * D + N_NODES * 3) / 4;
    init_out_kernel<<<(NT4 + 255) / 256, 256, 0, stream>>>(h, x, out);
    edge_kernel<<<(N_EDGES + 255) / 256, 256, 0, stream>>>(
        h, x, eidx, Wh, bh, Wx, bx, out);
    return;
  }

  __half2* M16 = (__half2*)d_ws;
  float4*  px  = (float4*)((char*)d_ws + (size_t)N_NODES * D * 2);
  int*     bins = (int*)((char*)px + (size_t)N_NODES * 16);
  int*     gcur = bins + (size_t)NBIN * BCAP;

  hipMemsetAsync(gcur, 0, NBIN * sizeof(int), stream);
  pre_bin_kernel<<<NBINBLK + PREBLK, BLOCK, 0, stream>>>(
      h, x, eidx, Wh, bh, Wx, bx, M16, px, bins, gcur);
  agg_kernel<<<NBIN * SUBS, 256, 0, stream>>>(
      h, x, bins, gcur, M16, px, out);
}